// Round 4
// baseline (58.008 us; speedup 1.0000x reference)
//
#include <hip/hip_runtime.h>
#include <hip/hip_bf16.h>

#define BB 2
#define DD 160
#define HH 192
#define WW 160

// Block = 32(w) x 8(h) threads, each thread does 4 d-slices.
// 1D grid of 9600 blocks, XCD-swizzled: block id -> (xcd = id&7) owns a
// contiguous 10-slab z-range; within an XCD, (x,y) varies fastest so one
// d-slab (~640 KB of vol) is hot at a time and the XCD's total vol
// footprint (~5 MB) approximately fits its private 4 MB L2.

__device__ __forceinline__ float2 ld2(const float* p) {
    float2 v;
    __builtin_memcpy(&v, p, 8);   // global_load_dwordx2
    return v;
}

struct Gp {
    const float* r00;
    int d1o, h1o;
    float tw, th, td;
};

__device__ __forceinline__ Gp prep(const float* __restrict__ vb,
                                   float ld, float lh, float lw) {
    ld = fminf(fmaxf(ld, 0.0f), (float)(DD - 1));
    lh = fminf(fmaxf(lh, 0.0f), (float)(HH - 1));
    lw = fminf(fmaxf(lw, 0.0f), (float)(WW - 1));

    float fd0 = floorf(ld), fh0 = floorf(lh), fw0 = floorf(lw);

    int d0 = (int)fd0, h0 = (int)fh0, w0 = (int)fw0;
    int d1 = min(d0 + 1, DD - 1);
    int h1 = min(h0 + 1, HH - 1);
    int wp = min(w0, WW - 2);   // pair-load: exact (tw==0 when w0==W-1)

    Gp g;
    g.td = ld - fd0;
    g.th = lh - fh0;
    g.tw = (lw - fw0) + (float)(w0 - wp);
    g.d1o = (d1 - d0) * (HH * WW);
    g.h1o = (h1 - h0) * WW;
    g.r00 = vb + d0 * (HH * WW) + h0 * WW + wp;
    return g;
}

__device__ __forceinline__ float finish(const Gp& g, float2 a00, float2 a01,
                                        float2 a10, float2 a11) {
    float x00 = a00.x + g.tw * (a00.y - a00.x);
    float x01 = a01.x + g.tw * (a01.y - a01.x);
    float x10 = a10.x + g.tw * (a10.y - a10.x);
    float x11 = a11.x + g.tw * (a11.y - a11.x);
    float y0 = x00 + g.th * (x01 - x00);
    float y1 = x10 + g.th * (x11 - x10);
    return y0 + g.td * (y1 - y0);
}

__global__ void __launch_bounds__(256)
st_trilinear_xcd(const float* __restrict__ vol,
                 const float* __restrict__ shift,
                 float* __restrict__ out) {
    // XCD-aware decomposition of 9600 blocks = (5 x, 24 y, 80 z)
    int bid = blockIdx.x;
    int xcd = bid & 7;
    int rank = bid >> 3;           // 0..1199
    int zl = rank / 120;           // 0..9   (slab index within XCD, slowest)
    int xy = rank % 120;
    int by = xy / 5;               // 0..23
    int bx = xy - by * 5;          // 0..4
    int z = xcd * 10 + zl;         // 0..79
    int b = z / 40;
    int d0 = (z - b * 40) * 4;

    const int w = bx * 32 + threadIdx.x;
    const int h = by * 8 + threadIdx.y;

    const float* vb = vol + (long)b * (DD * HH * WW);
    const long sD = (long)HH * WW;
    const long idx = (((long)b * DD + d0) * HH + h) * WW + w;

    const float fh = (float)h, fw = (float)w;
    const float fd = (float)d0;

    // --- phase 1: all shift loads (independent, coalesced dwordx3) ---
    float3 s0, s1, s2, s3;
    __builtin_memcpy(&s0, shift + (idx + 0 * sD) * 3, 12);
    __builtin_memcpy(&s1, shift + (idx + 1 * sD) * 3, 12);
    __builtin_memcpy(&s2, shift + (idx + 2 * sD) * 3, 12);
    __builtin_memcpy(&s3, shift + (idx + 3 * sD) * 3, 12);

    // --- phase 2: all gather descriptors (VALU only) ---
    Gp g0 = prep(vb, fd + 0.0f + s0.x, fh + s0.y, fw + s0.z);
    Gp g1 = prep(vb, fd + 1.0f + s1.x, fh + s1.y, fw + s1.z);
    Gp g2 = prep(vb, fd + 2.0f + s2.x, fh + s2.y, fw + s2.z);
    Gp g3 = prep(vb, fd + 3.0f + s3.x, fh + s3.y, fw + s3.z);

    // --- phase 3: issue all 16 pair-gathers (max MLP) ---
    float2 a0_00 = ld2(g0.r00);
    float2 a0_01 = ld2(g0.r00 + g0.h1o);
    float2 a0_10 = ld2(g0.r00 + g0.d1o);
    float2 a0_11 = ld2(g0.r00 + g0.d1o + g0.h1o);

    float2 a1_00 = ld2(g1.r00);
    float2 a1_01 = ld2(g1.r00 + g1.h1o);
    float2 a1_10 = ld2(g1.r00 + g1.d1o);
    float2 a1_11 = ld2(g1.r00 + g1.d1o + g1.h1o);

    float2 a2_00 = ld2(g2.r00);
    float2 a2_01 = ld2(g2.r00 + g2.h1o);
    float2 a2_10 = ld2(g2.r00 + g2.d1o);
    float2 a2_11 = ld2(g2.r00 + g2.d1o + g2.h1o);

    float2 a3_00 = ld2(g3.r00);
    float2 a3_01 = ld2(g3.r00 + g3.h1o);
    float2 a3_10 = ld2(g3.r00 + g3.d1o);
    float2 a3_11 = ld2(g3.r00 + g3.d1o + g3.h1o);

    // --- phase 4: finish + nontemporal stores ---
    __builtin_nontemporal_store(finish(g0, a0_00, a0_01, a0_10, a0_11), out + idx + 0 * sD);
    __builtin_nontemporal_store(finish(g1, a1_00, a1_01, a1_10, a1_11), out + idx + 1 * sD);
    __builtin_nontemporal_store(finish(g2, a2_00, a2_01, a2_10, a2_11), out + idx + 2 * sD);
    __builtin_nontemporal_store(finish(g3, a3_00, a3_01, a3_10, a3_11), out + idx + 3 * sD);
}

extern "C" void kernel_launch(void* const* d_in, const int* in_sizes, int n_in,
                              void* d_out, int out_size, void* d_ws, size_t ws_size,
                              hipStream_t stream) {
    const float* vol   = (const float*)d_in[0];
    const float* shift = (const float*)d_in[1];
    float* out = (float*)d_out;

    dim3 block(32, 8, 1);
    int grid = (WW / 32) * (HH / 8) * (DD / 4) * BB;   // 9600

    st_trilinear_xcd<<<grid, block, 0, stream>>>(vol, shift, out);
}